// Round 11
// baseline (322.989 us; speedup 1.0000x reference)
//
#include <hip/hip_runtime.h>
#include <hip/hip_bf16.h>
#include <math.h>

// SharedLora on MI355X — round 11.
// r10 (clean, no-spill, SGPR-comp) + in-block pipeline: TPB=4 tiles/block,
// double-buffered LDS U (43 KB), prefetch of the WIDE streams (p6 f4 + p5 f2,
// 36 staging regs) into registers while computing the previous tile (T14).
// Bias handled as row a==20 (uniform, no divergence). Coarse scalars
// (p4..p0, L1-hot across the block's tiles) loaded at ds_write time.
// r9's version of this died from a 48-VGPR launch-bounds cap; here (256,2).

#define NROI 256
#define NC 20
#define NFINAL 8000
#define NCUTS 500000
#define TB 256
#define NTILE 32           // 8000/256 -> tile 31 has 64 valid bins
#define TPB 4
#define NOCT (NTILE / TPB) // 8
#define NROWS 21           // 20 delta rows + 1 bias row
#define NUNITS (NROWS * 64)   // 1344

__global__ void k_init(const float* __restrict__ comp,
                       float* __restrict__ g2, float* __restrict__ compT,
                       float* __restrict__ kl)
{
    const int tid = threadIdx.x;
    if (tid == 0) kl[0] = (float)(-80076800.0 * 1.3244036413128371);
    for (int i = tid; i < 400; i += 256) {
        const int a = i / 20, b = i % 20;
        float s = 0.f;
#pragma unroll
        for (int c = 0; c < 20; c++) s += comp[a * 20 + c] * comp[b * 20 + c];
        // upper-triangular, off-diag doubled: q = sum_a x_a * sum_{b>=a} g2 x_b
        g2[i] = (b < a) ? 0.f : (b == a ? s : 2.f * s);
        compT[i] = comp[b * 20 + a];   // compT[c*20+a] = comp[a*20+c]
    }
}

__global__ __launch_bounds__(256, 2) void k_main(
    const float* __restrict__ compT, const float* __restrict__ g2,
    const float* __restrict__ wb0, const float* __restrict__ wd0,
    const float* __restrict__ wb1, const float* __restrict__ wd1,
    const float* __restrict__ wb2, const float* __restrict__ wd2,
    const float* __restrict__ wb3, const float* __restrict__ wd3,
    const float* __restrict__ wb4, const float* __restrict__ wd4,
    const float* __restrict__ wb5, const float* __restrict__ wd5,
    const float* __restrict__ wb6, const float* __restrict__ wd6,
    const int* __restrict__ regions_oi,
    __hip_bfloat16* __restrict__ w2,
    float* __restrict__ s_part, float* __restrict__ kl_out)
{
    __shared__ float U_sh[2][NROWS * TB];   // 2 x 21 KiB
    __shared__ float klp[4];

    const int tid = threadIdx.x;
    const int wv = tid >> 6, lane = tid & 63;
    const int r = blockIdx.x >> 3;      // 256 regions
    const int oct = blockIdx.x & 7;     // 8 octs x 4 tiles
    const int t0 = oct * TPB;
    const int r0 = regions_oi[r];

    const float* __restrict__ p6 = wd6 + (size_t)r0 * (20 * 8000);
    const float* __restrict__ p5 = wd5 + (size_t)r0 * (20 * 4000);
    const float* __restrict__ p4 = wd4 + (size_t)r0 * (20 * 2000);
    const float* __restrict__ p3 = wd3 + (size_t)r0 * (20 * 1000);
    const float* __restrict__ p2 = wd2 + (size_t)r0 * (20 * 400);
    const float* __restrict__ p1 = wd1 + (size_t)r0 * (20 * 200);
    const float* __restrict__ p0 = wd0 + (size_t)r0 * (20 * 40);
    const float* __restrict__ b6 = wb6 + (size_t)r0 * 8000;
    const float* __restrict__ b5 = wb5 + (size_t)r0 * 4000;
    const float* __restrict__ b4 = wb4 + (size_t)r0 * 2000;
    const float* __restrict__ b3 = wb3 + (size_t)r0 * 1000;
    const float* __restrict__ b2 = wb2 + (size_t)r0 * 400;
    const float* __restrict__ b1 = wb1 + (size_t)r0 * 200;
    const float* __restrict__ b0 = wb0 + (size_t)r0 * 40;

    // staging registers: wide streams only (6 units x 6 floats = 36 regs)
    float4 r6[6];
    float2 r5[6];

    auto LOADR = [&](int tl) {
#pragma unroll
        for (int k = 0; k < 6; k++) {
            const int u = tid + (k << 8);
            if (u < NUNITS) {
                const int a = u >> 6, jq = u & 63;
                const int j = (tl << 8) + 4 * jq;
                const float* q6 = (a < 20) ? p6 + (size_t)a * 8000 : b6;
                const float* q5 = (a < 20) ? p5 + (size_t)a * 4000 : b5;
                if (j < NFINAL) {
                    r6[k] = *(const float4*)(q6 + j);
                    r5[k] = *(const float2*)(q5 + (j >> 1));
                } else {
                    r6[k] = make_float4(0.f, 0.f, 0.f, 0.f);
                    r5[k] = make_float2(0.f, 0.f);
                }
            }
        }
    };

    auto WRITEF = [&](int buf, int tl) {
#pragma unroll
        for (int k = 0; k < 6; k++) {
            const int u = tid + (k << 8);
            if (u < NUNITS) {
                const int a = u >> 6, jq = u & 63;
                const int j = (tl << 8) + 4 * jq;
                const float *q4, *q3, *q2, *q1, *q0;
                if (a < 20) {
                    q4 = p4 + (size_t)a * 2000; q3 = p3 + (size_t)a * 1000;
                    q2 = p2 + (size_t)a * 400;  q1 = p1 + (size_t)a * 200;
                    q0 = p0 + (size_t)a * 40;
                } else {
                    q4 = b4; q3 = b3; q2 = b2; q1 = b1; q0 = b0;
                }
                float sc = 0.f;
                if (j < NFINAL)
                    sc = q4[j >> 2] + q3[j >> 3] + q2[j / 20] + q1[j / 40]
                       + q0[j / 200];
                const float c01 = sc + r5[k].x, c23 = sc + r5[k].y;
                float4 uu;
                uu.x = r6[k].x + c01; uu.y = r6[k].y + c01;
                uu.z = r6[k].z + c23; uu.w = r6[k].w + c23;
                *(float4*)(&U_sh[buf][a * TB + 4 * jq]) = uu;
            }
        }
    };

    const int cb = __builtin_amdgcn_readfirstlane(wv * 5);
    const float* __restrict__ cc = compT + cb * 20;   // uniform -> s_load

    auto PAF = [&](int buf, int tl) {
        const int j = (tl << 8) + 4 * lane;
        const bool ok = j < NFINAL;
        const float4 bi = *(const float4*)(&U_sh[buf][20 * TB + 4 * lane]);
        {   // pass A: clusters cb, cb+1, cb+2
            float4 a0 = bi, a1 = bi, a2 = bi;
#pragma unroll
            for (int a = 0; a < 20; a++) {
                const float4 u = *(const float4*)(&U_sh[buf][a * TB + 4 * lane]);
                const float f0 = cc[a], f1 = cc[20 + a], f2 = cc[40 + a];
                a0.x += f0 * u.x; a0.y += f0 * u.y; a0.z += f0 * u.z; a0.w += f0 * u.w;
                a1.x += f1 * u.x; a1.y += f1 * u.y; a1.z += f1 * u.z; a1.w += f1 * u.w;
                a2.x += f2 * u.x; a2.y += f2 * u.y; a2.z += f2 * u.z; a2.w += f2 * u.w;
            }
            float4 accs[3] = {a0, a1, a2};
#pragma unroll
            for (int k = 0; k < 3; k++) {
                float se = 0.f;
                if (ok) {
                    const float4 acc = accs[k];
                    union { __hip_bfloat162 h2[2]; uint2 u2; } pk;
                    pk.h2[0] = __float22bfloat162_rn(make_float2(acc.x, acc.y));
                    pk.h2[1] = __float22bfloat162_rn(make_float2(acc.z, acc.w));
                    *(uint2*)(w2 + (size_t)(r * 20 + cb + k) * 8000 + j) = pk.u2;
                    // |w| small (~<4): unnormalized exp-sum safe in f32
                    se = __expf(acc.x) + __expf(acc.y) + __expf(acc.z) + __expf(acc.w);
                }
#pragma unroll
                for (int off = 32; off > 0; off >>= 1) se += __shfl_down(se, off, 64);
                if (lane == 0) s_part[((size_t)r * NTILE + tl) * 20 + cb + k] = se;
            }
        }
        {   // pass B: clusters cb+3, cb+4
            float4 a0 = bi, a1 = bi;
#pragma unroll
            for (int a = 0; a < 20; a++) {
                const float4 u = *(const float4*)(&U_sh[buf][a * TB + 4 * lane]);
                const float f0 = cc[60 + a], f1 = cc[80 + a];
                a0.x += f0 * u.x; a0.y += f0 * u.y; a0.z += f0 * u.z; a0.w += f0 * u.w;
                a1.x += f1 * u.x; a1.y += f1 * u.y; a1.z += f1 * u.z; a1.w += f1 * u.w;
            }
            float4 accs[2] = {a0, a1};
#pragma unroll
            for (int k = 0; k < 2; k++) {
                float se = 0.f;
                if (ok) {
                    const float4 acc = accs[k];
                    union { __hip_bfloat162 h2[2]; uint2 u2; } pk;
                    pk.h2[0] = __float22bfloat162_rn(make_float2(acc.x, acc.y));
                    pk.h2[1] = __float22bfloat162_rn(make_float2(acc.z, acc.w));
                    *(uint2*)(w2 + (size_t)(r * 20 + cb + 3 + k) * 8000 + j) = pk.u2;
                    se = __expf(acc.x) + __expf(acc.y) + __expf(acc.z) + __expf(acc.w);
                }
#pragma unroll
                for (int off = 32; off > 0; off >>= 1) se += __shfl_down(se, off, 64);
                if (lane == 0) s_part[((size_t)r * NTILE + tl) * 20 + cb + 3 + k] = se;
            }
        }
    };

    float q = 0.f;
    auto PQF = [&](int tl) {
        const int base = tl << 8;
#pragma unroll 1
        for (int it = 0; it < 2; it++) {
            const int u = it * 256 + tid;
            if (u >= 480) break;
            const float* P; int K, col;
            if (u < 256)      { P = p6; K = 8000; col = base + u; }
            else if (u < 384) { P = p5; K = 4000; col = (base >> 1) + (u - 256); }
            else if (u < 448) { P = p4; K = 2000; col = (base >> 2) + (u - 384); }
            else              { P = p3; K = 1000; col = (base >> 3) + (u - 448); }
            if (col < K) {
                float x[20];
#pragma unroll
                for (int a = 0; a < 20; a++) x[a] = P[(size_t)a * K + col];
#pragma unroll
                for (int a = 0; a < 20; a++) {
                    float t = g2[a * 21] * x[a];      // const offsets -> s_load
#pragma unroll
                    for (int b = a + 1; b < 20; b++) t += g2[a * 20 + b] * x[b];
                    q += x[a] * t;
                }
            }
        }
    };

    // ---- pipelined main loop: one barrier per tile ----
    LOADR(t0);
    WRITEF(0, t0);
    __syncthreads();
#pragma unroll 1
    for (int t = 0; t < TPB; t++) {
        const int tl = t0 + t;
        if (t < TPB - 1) LOADR(tl + 1);    // issue next tile's HBM loads early
        PAF(t & 1, tl);
        PQF(tl);
        if (t < TPB - 1) {
            WRITEF((t + 1) & 1, tl + 1);   // land prefetch in other buffer
            __syncthreads();
        }
    }

    // ---- KL reduction ----
#pragma unroll
    for (int off = 32; off > 0; off >>= 1) q += __shfl_down(q, off, 64);
    if (lane == 0) klp[wv] = q;
    __syncthreads();
    if (tid == 0)
        atomicAdd(kl_out, (klp[0] + klp[1] + klp[2] + klp[3]) * (-0.5f / 2.25f));
}

// KL quads for levels 0..2 (40+200+400 = 640 cols per region)
__global__ __launch_bounds__(256, 2) void k_klc(
    const float* __restrict__ g2,
    const float* __restrict__ wd0, const float* __restrict__ wd1,
    const float* __restrict__ wd2,
    const int* __restrict__ regions_oi, float* __restrict__ kl_out)
{
    __shared__ float klp[4];
    const int tid = threadIdx.x;
    const int r0 = regions_oi[blockIdx.x];
    const float* __restrict__ p2 = wd2 + (size_t)r0 * (20 * 400);
    const float* __restrict__ p1 = wd1 + (size_t)r0 * (20 * 200);
    const float* __restrict__ p0 = wd0 + (size_t)r0 * (20 * 40);

    float q = 0.f;
#pragma unroll 1
    for (int it = 0; it < 3; it++) {
        const int u = it * 256 + tid;
        if (u >= 640) break;
        const float* P; int K, col;
        if (u < 400)      { P = p2; K = 400; col = u; }
        else if (u < 600) { P = p1; K = 200; col = u - 400; }
        else              { P = p0; K = 40;  col = u - 600; }
        float x[20];
#pragma unroll
        for (int a = 0; a < 20; a++) x[a] = P[a * K + col];
#pragma unroll
        for (int a = 0; a < 20; a++) {
            float t = g2[a * 21] * x[a];
#pragma unroll
            for (int b = a + 1; b < 20; b++) t += g2[a * 20 + b] * x[b];
            q += x[a] * t;
        }
    }
#pragma unroll
    for (int off = 32; off > 0; off >>= 1) q += __shfl_down(q, off, 64);
    if ((tid & 63) == 0) klp[tid >> 6] = q;
    __syncthreads();
    if (tid == 0)
        atomicAdd(kl_out, (klp[0] + klp[1] + klp[2] + klp[3]) * (-0.5f / 2.25f));
}

__global__ void k_sub(const float* __restrict__ s_part, float* __restrict__ sub)
{
    const int i = blockIdx.x * 256 + threadIdx.x;
    if (i >= NROI * NC) return;
    const int r = i / 20, c = i % 20;
    float s = 0.f;
#pragma unroll 1
    for (int t = 0; t < NTILE; t++) s += s_part[(size_t)(r * NTILE + t) * 20 + c];
    sub[i] = logf(s) + 3.2188758248682006f;   // + log(25)
}

__global__ void k_gather(const int* __restrict__ lri, const int* __restrict__ lci,
                         const int* __restrict__ cli, const int* __restrict__ coords,
                         const __hip_bfloat16* __restrict__ w2,
                         const float* __restrict__ sub,
                         float* __restrict__ out)
{
    const int i = blockIdx.x * 256 + threadIdx.x;
    if (i >= NCUTS) return;
    const int r = lri[i];
    const int c = cli[lci[i]];
    int co = coords[i];
    co = co < 0 ? 0 : (co > 199999 ? 199999 : co);
    const int bin = co / 25;
    const int rc = r * 20 + c;
    out[i] = __bfloat162float(w2[(size_t)rc * 8000 + bin]) - sub[rc];
}

extern "C" void kernel_launch(void* const* d_in, const int* in_sizes, int n_in,
                              void* d_out, int out_size, void* d_ws, size_t ws_size,
                              hipStream_t stream)
{
    const float* comp = (const float*)d_in[0];
    const float* wb[7];
    const float* wd[7];
    if (in_sizes[2] == 400000) {
        for (int l = 0; l < 7; l++) { wb[l] = (const float*)d_in[1 + 2 * l]; wd[l] = (const float*)d_in[2 + 2 * l]; }
    } else {
        for (int l = 0; l < 7; l++) { wb[l] = (const float*)d_in[1 + l]; wd[l] = (const float*)d_in[8 + l]; }
    }
    const int* regions_oi = (const int*)d_in[15];
    const int* lri   = (const int*)d_in[16];
    const int* lci   = (const int*)d_in[17];
    const int* cli   = (const int*)d_in[18];
    const int* coords= (const int*)d_in[19];
    float* out = (float*)d_out;

    __hip_bfloat16* w2 = (__hip_bfloat16*)d_ws;                     // 81.92 MB
    float* s_part = (float*)(w2 + (size_t)NROI * NC * NFINAL);      // 8192*20 f32
    float* sub    = s_part + (size_t)NROI * NTILE * 20;             // 5120 f32
    float* g2buf  = sub + NROI * NC;                                // 400 f32
    float* compT  = g2buf + 400;                                    // 400 f32
    const size_t need = (size_t)NROI * NC * NFINAL * 2
                      + ((size_t)NROI * NTILE * 20 + NROI * NC + 800) * sizeof(float);
    if (ws_size < need) return;

    k_init<<<1, 256, 0, stream>>>(comp, g2buf, compT, out + NCUTS);
    k_main<<<NROI * NOCT, 256, 0, stream>>>(compT, g2buf,
        wb[0], wd[0], wb[1], wd[1], wb[2], wd[2], wb[3], wd[3],
        wb[4], wd[4], wb[5], wd[5], wb[6], wd[6],
        regions_oi, w2, s_part, out + NCUTS);
    k_klc<<<NROI, 256, 0, stream>>>(g2buf, wd[0], wd[1], wd[2],
        regions_oi, out + NCUTS);
    k_sub<<<(NROI * NC + 255) / 256, 256, 0, stream>>>(s_part, sub);
    k_gather<<<(NCUTS + 255) / 256, 256, 0, stream>>>(lri, lci, cli, coords,
        w2, sub, out);
}

// Round 12
// 192.577 us; speedup vs baseline: 1.6772x; 1.6772x over previous
//
#include <hip/hip_runtime.h>
#include <hip/hip_bf16.h>
#include <math.h>

// SharedLora on MI355X — round 12: MFMA for both FMA blocks.
// r10 was VALU-bound (~860 FMA/thread). Here:
//   PA: w = bias + comp^T U  -> mfma_f32_16x16x32_bf16 (M=clusters pad32,
//       K=a pad32, N=bins).  B-frag from Ut[bin][a] bf16 LDS (bin-major).
//   PQ: kl_quad = tr(G * X X^T) -> syrk via MFMA on X[a][col] bf16 LDS
//       (L6/L5/L4/L3 cols of the tile; 3 unique S-tiles, off-diag doubled).
//   L0-2 quads in k_klc (unchanged). w stored bf16.
// Law (r1/r3/r6/r9/r11): no cross-phase register staging; consume-now P0.

#define NROI 256
#define NC 20
#define NFINAL 8000
#define NCUTS 500000
#define TB 256
#define NTILE 32           // 8000/256 -> tile 31 has 64 valid bins
#define XSTR 488           // X row stride (bf16 elems); 976B, 16B-aligned
#define UTSTR 40           // Ut row stride (bf16 elems); 80B

typedef __attribute__((ext_vector_type(8))) short bf16x8;
typedef __attribute__((ext_vector_type(4))) float f32x4;

static __device__ __forceinline__ ushort bfr(float x) {
    union { __hip_bfloat16 h; ushort u; } v;
    v.h = __float2bfloat16(x);
    return v.u;
}

__global__ void k_init(const float* __restrict__ comp,
                       float* __restrict__ g2, float* __restrict__ gfull,
                       ushort* __restrict__ compPad, float* __restrict__ kl)
{
    const int tid = threadIdx.x;
    if (tid == 0) kl[0] = (float)(-80076800.0 * 1.3244036413128371);
    for (int i = tid; i < 400; i += 256) {
        const int a = i / 20, b = i % 20;
        float s = 0.f;
#pragma unroll
        for (int c = 0; c < 20; c++) s += comp[a * 20 + c] * comp[b * 20 + c];
        g2[i] = (b < a) ? 0.f : (b == a ? s : 2.f * s);   // triangular (k_klc)
    }
    for (int i = tid; i < 1024; i += 256) {
        const int rr = i >> 5, cc = i & 31;
        float s = 0.f;
        if (rr < 20 && cc < 20) {
#pragma unroll
            for (int c = 0; c < 20; c++) s += comp[rr * 20 + c] * comp[cc * 20 + c];
        }
        gfull[i] = s;                                      // full Gram, 0-padded
        const float v = (rr < 20 && cc < 20) ? comp[cc * 20 + rr] : 0.f;
        compPad[i] = bfr(v);                               // compPad[cluster][a]
    }
}

__global__ __launch_bounds__(256, 2) void k_main(
    const float* __restrict__ gfull, const ushort* __restrict__ compPad,
    const float* __restrict__ wb0, const float* __restrict__ wd0,
    const float* __restrict__ wb1, const float* __restrict__ wd1,
    const float* __restrict__ wb2, const float* __restrict__ wd2,
    const float* __restrict__ wb3, const float* __restrict__ wd3,
    const float* __restrict__ wb4, const float* __restrict__ wd4,
    const float* __restrict__ wb5, const float* __restrict__ wd5,
    const float* __restrict__ wb6, const float* __restrict__ wd6,
    const int* __restrict__ regions_oi,
    __hip_bfloat16* __restrict__ w2,
    float* __restrict__ s_part, float* __restrict__ kl_out)
{
    __shared__ ushort Xsh[32 * XSTR];     // 31,232 B  raw levels (bf16)
    __shared__ ushort Utsh[TB * UTSTR];   // 20,480 B  folded U, bin-major (bf16)
    __shared__ float biasf[TB];           // 1 KiB
    __shared__ float sexp_sh[20];
    __shared__ float klp[3];

    const int tid = threadIdx.x;
    const int wv = tid >> 6, ln = tid & 63;
    const int l15 = ln & 15, lg = ln >> 4;
    const int r = blockIdx.x >> 5;
    const int tile = blockIdx.x & 31;
    const int base = tile << 8;
    const int r0 = regions_oi[r];

    const float* __restrict__ p6 = wd6 + (size_t)r0 * (20 * 8000);
    const float* __restrict__ p5 = wd5 + (size_t)r0 * (20 * 4000);
    const float* __restrict__ p4 = wd4 + (size_t)r0 * (20 * 2000);
    const float* __restrict__ p3 = wd3 + (size_t)r0 * (20 * 1000);
    const float* __restrict__ p2 = wd2 + (size_t)r0 * (20 * 400);
    const float* __restrict__ p1 = wd1 + (size_t)r0 * (20 * 200);
    const float* __restrict__ p0 = wd0 + (size_t)r0 * (20 * 40);
    const float* __restrict__ b6 = wb6 + (size_t)r0 * 8000;
    const float* __restrict__ b5 = wb5 + (size_t)r0 * 4000;
    const float* __restrict__ b4 = wb4 + (size_t)r0 * 2000;
    const float* __restrict__ b3 = wb3 + (size_t)r0 * 1000;
    const float* __restrict__ b2 = wb2 + (size_t)r0 * 400;
    const float* __restrict__ b1 = wb1 + (size_t)r0 * 200;
    const float* __restrict__ b0 = wb0 + (size_t)r0 * 40;

    if (tid < 20) sexp_sh[tid] = 0.f;
    if (tid < 3) klp[tid] = 0.f;

    // ---- Z: zero pad regions (whole Ut; X rows 20-31) ----
#pragma unroll 1
    for (int it = 0; it < 8; it++) {
        const int u = it * 256 + tid;
        if (u >= 2012) break;
        if (u < 1280) *(uint4*)&Utsh[u * 8] = make_uint4(0, 0, 0, 0);
        else          *(uint4*)&Xsh[20 * XSTR + (u - 1280) * 8] = make_uint4(0, 0, 0, 0);
    }
    __syncthreads();

    // ---- P0: stage (consume-now; unit = (row a|bias, jq lane)) ----
#pragma unroll 1
    for (int it = 0; it < 6; it++) {
        const int u = it * 256 + tid;
        if (u >= 1344) break;
        const int a = u >> 6, jq = u & 63;   // a uniform per wave
        const int j = base + 4 * jq;
        const float *q6, *q5, *q4, *q3, *q2, *q1, *q0;
        if (a < 20) {
            q6 = p6 + (size_t)a * 8000; q5 = p5 + a * 4000; q4 = p4 + a * 2000;
            q3 = p3 + a * 1000; q2 = p2 + a * 400; q1 = p1 + a * 200; q0 = p0 + a * 40;
        } else { q6 = b6; q5 = b5; q4 = b4; q3 = b3; q2 = b2; q1 = b1; q0 = b0; }
        float4 r6 = make_float4(0.f, 0.f, 0.f, 0.f);
        float2 r5 = make_float2(0.f, 0.f);
        float s4 = 0.f, s3 = 0.f, s2 = 0.f, s1 = 0.f, s0 = 0.f;
        if (j < NFINAL) {
            r6 = *(const float4*)(q6 + j);
            r5 = *(const float2*)(q5 + (j >> 1));
            s4 = q4[j >> 2]; s3 = q3[j >> 3]; s2 = q2[j / 20];
            s1 = q1[j / 40]; s0 = q0[j / 200];
        }
        const float sc = s4 + s3 + s2 + s1 + s0;
        const float c01 = sc + r5.x, c23 = sc + r5.y;
        const float u0 = r6.x + c01, u1 = r6.y + c01;
        const float u2 = r6.z + c23, u3 = r6.w + c23;
        if (a < 20) {
            // X: raw per-level values (KL syrk input)
            *(ushort4*)&Xsh[a * XSTR + 4 * jq] =
                make_ushort4(bfr(r6.x), bfr(r6.y), bfr(r6.z), bfr(r6.w));
            *(ushort2*)&Xsh[a * XSTR + 256 + 2 * jq] =
                make_ushort2(bfr(r5.x), bfr(r5.y));
            Xsh[a * XSTR + 384 + jq] = bfr(s4);
            if (!(jq & 1)) Xsh[a * XSTR + 448 + (jq >> 1)] = bfr(s3);
            // Ut: folded U, bin-major (w-proj B-frag input)
            Utsh[(4 * jq + 0) * UTSTR + a] = bfr(u0);
            Utsh[(4 * jq + 1) * UTSTR + a] = bfr(u1);
            Utsh[(4 * jq + 2) * UTSTR + a] = bfr(u2);
            Utsh[(4 * jq + 3) * UTSTR + a] = bfr(u3);
        } else {
            *(float4*)&biasf[4 * jq] = make_float4(u0, u1, u2, u3);
        }
    }
    __syncthreads();

    // ---- M1: syrk S = X X^T (waves 0-2 own tiles (0,0),(1,0),(1,1)) ----
    if (wv < 3) {
        const int mt = (wv == 0) ? 0 : 1;
        const int nt = (wv == 2) ? 1 : 0;
        const int rowA = mt * 16 + l15;
        const int rowB = nt * 16 + l15;
        const int kb = lg * 8;
        f32x4 acc = {0.f, 0.f, 0.f, 0.f};
#pragma unroll 1
        for (int ch = 0; ch < 15; ch++) {       // 15 x 32 = 480 columns
            bf16x8 fa = *(const bf16x8*)&Xsh[rowA * XSTR + ch * 32 + kb];
            bf16x8 fb = *(const bf16x8*)&Xsh[rowB * XSTR + ch * 32 + kb];
            acc = __builtin_amdgcn_mfma_f32_16x16x32_bf16(fa, fb, acc, 0, 0, 0);
        }
        float qp = 0.f;
#pragma unroll
        for (int reg = 0; reg < 4; reg++) {
            const int row = mt * 16 + lg * 4 + reg;
            const int col = nt * 16 + l15;
            qp += gfull[row * 32 + col] * acc[reg];
        }
        if (wv == 1) qp *= 2.f;                 // off-diagonal block counted twice
#pragma unroll
        for (int off = 32; off > 0; off >>= 1) qp += __shfl_down(qp, off, 64);
        if (ln == 0) klp[wv] = qp;
    }

    // ---- M2: w = bias + comp^T U via MFMA; all 4 waves, 4 n-tiles each ----
    bf16x8 fA0 = *(const bf16x8*)&compPad[l15 * 32 + lg * 8];        // clusters 0-15
    bf16x8 fA1 = *(const bf16x8*)&compPad[(16 + l15) * 32 + lg * 8]; // clusters 16-31
    float sA[4] = {0.f, 0.f, 0.f, 0.f};
    float sB[4] = {0.f, 0.f, 0.f, 0.f};
#pragma unroll 1
    for (int t = 0; t < 4; t++) {
        const int nt = 4 * t + wv;
        bf16x8 fB = *(const bf16x8*)&Utsh[(nt * 16 + l15) * UTSTR + lg * 8];
        const f32x4 z = {0.f, 0.f, 0.f, 0.f};
        f32x4 c0 = __builtin_amdgcn_mfma_f32_16x16x32_bf16(fA0, fB, z, 0, 0, 0);
        f32x4 c1 = __builtin_amdgcn_mfma_f32_16x16x32_bf16(fA1, fB, z, 0, 0, 0);
        const int binl = nt * 16 + l15;
        const int bin = base + binl;
        const float bi = biasf[binl];
        if (bin < NFINAL) {
#pragma unroll
            for (int reg = 0; reg < 4; reg++) {
                const int c = lg * 4 + reg;                 // clusters 0-15
                const float w = bi + c0[reg];
                w2[(size_t)(r * 20 + c) * 8000 + bin] = __float2bfloat16(w);
                sA[reg] += __expf(w);                       // |w|<~4: safe f32
            }
            if (lg == 0) {                                  // clusters 16-19
#pragma unroll
                for (int reg = 0; reg < 4; reg++) {
                    const float w = bi + c1[reg];
                    w2[(size_t)(r * 20 + 16 + reg) * 8000 + bin] = __float2bfloat16(w);
                    sB[reg] += __expf(w);
                }
            }
        }
    }
    // reduce exp-sums over the 16 bin-lanes, accumulate per cluster
#pragma unroll
    for (int reg = 0; reg < 4; reg++) {
        float s = sA[reg];
        s += __shfl_xor(s, 1, 64); s += __shfl_xor(s, 2, 64);
        s += __shfl_xor(s, 4, 64); s += __shfl_xor(s, 8, 64);
        if (l15 == 0) atomicAdd(&sexp_sh[lg * 4 + reg], s);
        float sb = sB[reg];
        sb += __shfl_xor(sb, 1, 64); sb += __shfl_xor(sb, 2, 64);
        sb += __shfl_xor(sb, 4, 64); sb += __shfl_xor(sb, 8, 64);
        if (ln == 0) atomicAdd(&sexp_sh[16 + reg], sb);
    }
    __syncthreads();
    if (tid < 20) s_part[((size_t)r * NTILE + tile) * 20 + tid] = sexp_sh[tid];
    if (tid == 0)
        atomicAdd(kl_out, (klp[0] + klp[1] + klp[2]) * (-0.5f / 2.25f));
}

// KL quads for levels 0..2 (40+200+400 = 640 cols per region)
__global__ __launch_bounds__(256, 2) void k_klc(
    const float* __restrict__ g2,
    const float* __restrict__ wd0, const float* __restrict__ wd1,
    const float* __restrict__ wd2,
    const int* __restrict__ regions_oi, float* __restrict__ kl_out)
{
    __shared__ float klp[4];
    const int tid = threadIdx.x;
    const int r0 = regions_oi[blockIdx.x];
    const float* __restrict__ p2 = wd2 + (size_t)r0 * (20 * 400);
    const float* __restrict__ p1 = wd1 + (size_t)r0 * (20 * 200);
    const float* __restrict__ p0 = wd0 + (size_t)r0 * (20 * 40);

    float q = 0.f;
#pragma unroll 1
    for (int it = 0; it < 3; it++) {
        const int u = it * 256 + tid;
        if (u >= 640) break;
        const float* P; int K, col;
        if (u < 400)      { P = p2; K = 400; col = u; }
        else if (u < 600) { P = p1; K = 200; col = u - 400; }
        else              { P = p0; K = 40;  col = u - 600; }
        float x[20];
#pragma unroll
        for (int a = 0; a < 20; a++) x[a] = P[a * K + col];
#pragma unroll
        for (int a = 0; a < 20; a++) {
            float t = g2[a * 21] * x[a];
#pragma unroll
            for (int b = a + 1; b < 20; b++) t += g2[a * 20 + b] * x[b];
            q += x[a] * t;
        }
    }
#pragma unroll
    for (int off = 32; off > 0; off >>= 1) q += __shfl_down(q, off, 64);
    if ((tid & 63) == 0) klp[tid >> 6] = q;
    __syncthreads();
    if (tid == 0)
        atomicAdd(kl_out, (klp[0] + klp[1] + klp[2] + klp[3]) * (-0.5f / 2.25f));
}

__global__ void k_sub(const float* __restrict__ s_part, float* __restrict__ sub)
{
    const int i = blockIdx.x * 256 + threadIdx.x;
    if (i >= NROI * NC) return;
    const int r = i / 20, c = i % 20;
    float s = 0.f;
#pragma unroll 1
    for (int t = 0; t < NTILE; t++) s += s_part[(size_t)(r * NTILE + t) * 20 + c];
    sub[i] = logf(s) + 3.2188758248682006f;   // + log(25)
}

__global__ void k_gather(const int* __restrict__ lri, const int* __restrict__ lci,
                         const int* __restrict__ cli, const int* __restrict__ coords,
                         const __hip_bfloat16* __restrict__ w2,
                         const float* __restrict__ sub,
                         float* __restrict__ out)
{
    const int i = blockIdx.x * 256 + threadIdx.x;
    if (i >= NCUTS) return;
    const int r = lri[i];
    const int c = cli[lci[i]];
    int co = coords[i];
    co = co < 0 ? 0 : (co > 199999 ? 199999 : co);
    const int bin = co / 25;
    const int rc = r * 20 + c;
    out[i] = __bfloat162float(w2[(size_t)rc * 8000 + bin]) - sub[rc];
}

extern "C" void kernel_launch(void* const* d_in, const int* in_sizes, int n_in,
                              void* d_out, int out_size, void* d_ws, size_t ws_size,
                              hipStream_t stream)
{
    const float* comp = (const float*)d_in[0];
    const float* wb[7];
    const float* wd[7];
    if (in_sizes[2] == 400000) {
        for (int l = 0; l < 7; l++) { wb[l] = (const float*)d_in[1 + 2 * l]; wd[l] = (const float*)d_in[2 + 2 * l]; }
    } else {
        for (int l = 0; l < 7; l++) { wb[l] = (const float*)d_in[1 + l]; wd[l] = (const float*)d_in[8 + l]; }
    }
    const int* regions_oi = (const int*)d_in[15];
    const int* lri   = (const int*)d_in[16];
    const int* lci   = (const int*)d_in[17];
    const int* cli   = (const int*)d_in[18];
    const int* coords= (const int*)d_in[19];
    float* out = (float*)d_out;

    __hip_bfloat16* w2 = (__hip_bfloat16*)d_ws;                     // 81.92 MB
    float* s_part = (float*)(w2 + (size_t)NROI * NC * NFINAL);      // 8192*20 f32
    float* sub    = s_part + (size_t)NROI * NTILE * 20;             // 5120 f32
    float* g2buf  = sub + NROI * NC;                                // 400 f32
    float* gfull  = g2buf + 400;                                    // 1024 f32
    ushort* compPad = (ushort*)(gfull + 1024);                      // 1024 u16
    const size_t need = (size_t)NROI * NC * NFINAL * 2
                      + ((size_t)NROI * NTILE * 20 + NROI * NC + 400 + 1024 + 512)
                        * sizeof(float);
    if (ws_size < need) return;

    k_init<<<1, 256, 0, stream>>>(comp, g2buf, gfull, compPad, out + NCUTS);
    k_main<<<NROI * NTILE, 256, 0, stream>>>(gfull, compPad,
        wb[0], wd[0], wb[1], wd[1], wb[2], wd[2], wb[3], wd[3],
        wb[4], wd[4], wb[5], wd[5], wb[6], wd[6],
        regions_oi, w2, s_part, out + NCUTS);
    k_klc<<<NROI, 256, 0, stream>>>(g2buf, wd[0], wd[1], wd[2],
        regions_oi, out + NCUTS);
    k_sub<<<(NROI * NC + 255) / 256, 256, 0, stream>>>(s_part, sub);
    k_gather<<<(NCUTS + 255) / 256, 256, 0, stream>>>(lri, lci, cli, coords,
        w2, sub, out);
}